// Round 9
// baseline (378.971 us; speedup 1.0000x reference)
//
#include <hip/hip_runtime.h>
#include <cstdint>
#include <cstddef>

#define BB 256
#define TT 512
#define KK 128
#define START_TAG 126
#define STOP_TAG 127
#define NEGV (-10000.0f)
#define NINF (-__builtin_huge_valf())

// ---- DPP helpers -----------------------------------------------------------
template<int CTRL>
__device__ __forceinline__ float dppf(float v, float old) {
  return __int_as_float(__builtin_amdgcn_update_dpp(
      __float_as_int(old), __float_as_int(v), CTRL, 0xf, 0xf, false));
}
template<int CTRL>
__device__ __forceinline__ int dppi(int v, int old) {
  return __builtin_amdgcn_update_dpp(old, v, CTRL, 0xf, 0xf, false);
}
__device__ __forceinline__ float wave_max63(float x) {
  x = fmaxf(x, dppf<0x111>(x, NINF));
  x = fmaxf(x, dppf<0x112>(x, NINF));
  x = fmaxf(x, dppf<0x114>(x, NINF));
  x = fmaxf(x, dppf<0x118>(x, NINF));
  x = fmaxf(x, dppf<0x142>(x, NINF));
  x = fmaxf(x, dppf<0x143>(x, NINF));
  return x;
}
__device__ __forceinline__ float max3f(float a, float b, float c) {
  float d;
  asm("v_max3_f32 %0, %1, %2, %3" : "=v"(d) : "v"(a), "v"(b), "v"(c));
  return d;
}
__device__ __forceinline__ int paddr(int i) { return (i >> 5) * 36 + (i & 31); }

// ---------------------------------------------------------------------------
// crf1024: one block per b, 1024 threads (16 waves, 4/SIMD).
//   tid [0,512)    : Viterbi values (to=q>>2, h=q&3 -> 32-from slice R[32]).
//   tid [512,1024) : forward-alg (same split, R[32]=exp slice), log-free
//                    multiplicative recurrence, rescale every 4 steps;
//                    fused gold score.
// R[32] made OPAQUE via empty asm after init: defeats LLVM's loop-invariant-
// load rematerialization (the R8 pathology: VGPR=40, trans re-fetched every
// step). LDS reads: 4 distinct float4 addresses per wave (bases h*36) =
// R3-proven conflict-free broadcast. One barrier per step.
// ---------------------------------------------------------------------------
__global__ __launch_bounds__(1024, 4) void crf1024(
    const float* __restrict__ feats, const float* __restrict__ trans,
    const int* __restrict__ tags,
    float* __restrict__ pscore, int* __restrict__ lasttag,
    float* __restrict__ alphaS, float* __restrict__ gb)
{
  const int b = blockIdx.x;
  const int tid = threadIdx.x;
  const bool isv = tid < 512;
  const int q = isv ? tid : tid - 512;
  const int to = q >> 2;               // 0..127
  const int h  = q & 3;                // 32-from slice
  const int lane = tid & 63;
  const int wv = tid >> 6;             // 0..15

  __shared__ __align__(16) float AV[2][144];   // viterbi alpha (padded)
  __shared__ __align__(16) float P [2][144];   // fwd message (padded)
  __shared__ __align__(16) float pwm[8];       // fwd per-wave P-max
  __shared__ float vitm[2]; __shared__ int viti[2];
  __shared__ float reds[2]; __shared__ float redg[8];

  // 32-from transition slice in registers: raw (vit) / exp (fwd)
  float R[32];
  {
    const float4* tr = (const float4*)(trans + (size_t)to * KK + h * 32);
#pragma unroll
    for (int c = 0; c < 8; ++c) {
      float4 v = tr[c];
      if (isv) { R[4*c+0]=v.x; R[4*c+1]=v.y; R[4*c+2]=v.z; R[4*c+3]=v.w; }
      else     { R[4*c+0]=__expf(v.x); R[4*c+1]=__expf(v.y);
                 R[4*c+2]=__expf(v.z); R[4*c+3]=__expf(v.w); }
    }
  }
  // Defeat rematerialization: values become opaque, must stay in VGPRs.
#pragma unroll
  for (int c = 0; c < 32; ++c) asm volatile("" : "+v"(R[c]));

  if (isv) { if (h == 0) AV[0][paddr(to)] = (to==START_TAG)?0.0f:NEGV; }
  else     { if (h == 0) P[0][paddr(to)]  = (to==START_TAG)?1.0f:0.0f; }
  __syncthreads();

  const float* fb = feats + (size_t)b * TT * KK + to;
  float* aSb = alphaS + (size_t)b * TT * KK + to;

  float M = 0.0f;                 // fwd accumulated log-scale
  float fcur = fb[0];
  int cur = 0;

#pragma unroll 4
  for (int t = 0; t < TT; ++t) {
    const int tn = (t + 1 < TT) ? t + 1 : t;
    float fnext = fb[(size_t)tn * KK];

    if (isv) {
      const float* Ac = &AV[cur][0];
      const int base = h * 36;
      float4 p = *(const float4*)&Ac[base];
      float m0 = fmaxf(p.x + R[0], p.y + R[1]);
      float m1 = fmaxf(p.z + R[2], p.w + R[3]);
#pragma unroll
      for (int c = 1; c < 8; ++c) {
        p = *(const float4*)&Ac[base + c * 4];
        m0 = max3f(m0, p.x + R[4*c+0], p.y + R[4*c+1]);
        m1 = max3f(m1, p.z + R[4*c+2], p.w + R[4*c+3]);
      }
      float m = fmaxf(m0, m1);
      m = fmaxf(m, dppf<0xB1>(m, m));       // merge h pairs
      m = fmaxf(m, dppf<0x4E>(m, m));       // merge quad
      if (h == 0) {
        float a = m + fcur;
        AV[cur ^ 1][paddr(to)] = a;
        __builtin_nontemporal_store(a, &aSb[(size_t)t * KK]);
      }
    } else {
      float corr = 1.0f;
      if ((t & 3) == 0 && t) {              // consume previous phase-3 maxes
        float4 w0 = *(const float4*)&pwm[0];
        float4 w1 = *(const float4*)&pwm[4];
        float pmax = fmaxf(fmaxf(fmaxf(w0.x, w0.y), fmaxf(w0.z, w0.w)),
                           fmaxf(fmaxf(w1.x, w1.y), fmaxf(w1.z, w1.w)));
        M += __logf(pmax);
        corr = 1.0f / pmax;
      }
      const float* Pc = &P[cur][0];
      const int base = h * 36;
      float s0=0.f, s1=0.f, s2=0.f, s3=0.f;
#pragma unroll
      for (int c = 0; c < 8; ++c) {
        float4 p = *(const float4*)&Pc[base + c * 4];
        s0 = fmaf(R[4*c+0], p.x, s0);
        s1 = fmaf(R[4*c+1], p.y, s1);
        s2 = fmaf(R[4*c+2], p.z, s2);
        s3 = fmaf(R[4*c+3], p.w, s3);
      }
      float s = (s0 + s1) + (s2 + s3);
      s = s + dppf<0xB1>(s, s);             // merge h pairs
      s = s + dppf<0x4E>(s, s);             // merge quad
      float ef = __expf(fcur);
      if ((t & 3) == 0 && t) ef *= corr;
      float pv = s * ef;                    // P_new (scaled)
      if (h == 0) P[cur ^ 1][paddr(to)] = pv;
      if ((t & 3) == 3) {                   // publish wave max of P
        float wm = wave_max63(pv);
        if (lane == 63) pwm[wv - 8] = wm;
      }
    }
    __syncthreads();
    cur ^= 1;
    fcur = fnext;
  }

  // ---- terminal ----
  if (tid < KK) {
    // viterbi argmax over final alpha (exact first-index tie rule)
    float term = AV[cur][paddr(tid)] + trans[(size_t)STOP_TAG * KK + tid];
    float m = term; int i = tid;
#pragma unroll
    for (int off = 1; off < 64; off <<= 1) {
      float mo = __shfl_xor(m, off, 64);
      int   io = __shfl_xor(i, off, 64);
      if (mo > m || (mo == m && io < i)) { m = mo; i = io; }
    }
    if (lane == 0) { vitm[tid >> 6] = m; viti[tid >> 6] = i; }
  }
  if (tid >= 512 && tid < 512 + KK) {
    const int to2 = tid - 512;
    float e = P[cur][paddr(to2)] * __expf(trans[(size_t)STOP_TAG * KK + to2]);
#pragma unroll
    for (int off = 1; off < 64; off <<= 1) e += __shfl_xor(e, off, 64);
    if (lane == 0) reds[to2 >> 6] = e;
  }
  if (!isv) {
    // fused gold score: one time-step per fwd thread (q = t)
    const int* tg = tags + (size_t)b * TT;
    const float* fg = feats + (size_t)b * TT * KK;
    int ct = tg[q];
    int pv2 = (q == 0) ? START_TAG : tg[q - 1];
    float g = trans[(size_t)ct * KK + pv2] + fg[(size_t)q * KK + ct];
    if (q == TT - 1) g += trans[(size_t)STOP_TAG * KK + ct];
#pragma unroll
    for (int off = 1; off < 64; off <<= 1) g += __shfl_xor(g, off, 64);
    if (lane == 0) redg[wv - 8] = g;
  }
  __syncthreads();
  if (tid == 0) {
    float m = vitm[0]; int i = viti[0];
    if (vitm[1] > m || (vitm[1] == m && viti[1] < i)) { m = vitm[1]; i = viti[1]; }
    pscore[b] = m; lasttag[b] = i;
  }
  if (tid == 512) {
    float sg = redg[0]+redg[1]+redg[2]+redg[3]+redg[4]+redg[5]+redg[6]+redg[7];
    gb[b] = (M + __logf(reds[0] + reds[1])) - sg;
  }
}

// ---------------------------------------------------------------------------
// backtrace_loss: blocks [0,BB) backtrace per b; block BB reduces loss.
// ---------------------------------------------------------------------------
__global__ __launch_bounds__(64) void backtrace_loss(
    const float* __restrict__ alphaS, const float* __restrict__ trans,
    const int* __restrict__ lasttag, const float* __restrict__ gb,
    float* __restrict__ pred, float* __restrict__ loss_out)
{
  const int lane = threadIdx.x;
  if (blockIdx.x == BB) {
    float v = gb[lane] + gb[lane + 64] + gb[lane + 128] + gb[lane + 192];
#pragma unroll
    for (int off = 1; off < 64; off <<= 1) v += __shfl_xor(v, off, 64);
    if (lane == 0) loss_out[0] = v / (float)(BB * TT);
    return;
  }
  const int b = blockIdx.x;
  __shared__ float tl[KK * KK];                 // 64 KB
  {
    const float4* src = (const float4*)trans;
    float4* dst = (float4*)tl;
#pragma unroll
    for (int i = 0; i < (KK * KK / 4) / 64; ++i) dst[lane + i * 64] = src[lane + i * 64];
  }
  int tag = lasttag[b];
  if (lane == 0) pred[(size_t)b * TT + (TT - 1)] = (float)tag;
  const float* arow = alphaS + (size_t)b * TT * KK;

  float p0[8], p1[8];
#pragma unroll
  for (int j = 0; j < 8; ++j) {
    int r = TT - 2 - j;
    p0[j] = arow[(size_t)r * KK + lane];
    p1[j] = arow[(size_t)r * KK + 64 + lane];
  }
  __syncthreads();

  for (int rb = TT - 2; rb >= 0; rb -= 8) {
#pragma unroll
    for (int j = 0; j < 8; ++j) {
      int r = rb - j;
      if (r >= 0) {
        float x0 = p0[j] + tl[tag * KK + lane];
        float x1 = p1[j] + tl[tag * KK + 64 + lane];
        float m = fmaxf(x0, x1);
        float M = wave_max63(m);
        M = __int_as_float(__builtin_amdgcn_readlane(__float_as_int(M), 63));
        unsigned long long b0 = __ballot(x0 == M);
        unsigned long long b1 = __ballot(x1 == M);
        tag = b0 ? (int)__builtin_ctzll(b0) : 64 + (int)__builtin_ctzll(b1);
        if (lane == 0) pred[(size_t)b * TT + r] = (float)tag;
        int rp = r - 8;
        if (rp >= 0) {
          p0[j] = arow[(size_t)rp * KK + lane];
          p1[j] = arow[(size_t)rp * KK + 64 + lane];
        }
      }
    }
  }
}

// ===========================================================================
// Fallback path (ws too small for 64MB alpha store): R2-proven kernels.
// ===========================================================================
__global__ __launch_bounds__(768) void crf_main_fb(
    const float* __restrict__ feats, const float* __restrict__ trans,
    float* __restrict__ logz, float* __restrict__ pscore,
    int* __restrict__ lasttag, uint8_t* __restrict__ bptr)
{
  const int b = blockIdx.x;
  const int tid = threadIdx.x;
  const bool is_fwd = tid < 256;
  const int lane = tid & 63;

  __shared__ __align__(16) float P[2][144];
  __shared__ __align__(16) float AV[2][144];
  __shared__ __align__(16) float redmF[2][4];
  __shared__ float reds[4];
  __shared__ float vitm[8];
  __shared__ int   viti[8];

  int myto, h;
  if (is_fwd) { myto = tid >> 1; h = tid & 1; }
  else { int q = tid - 256; myto = q >> 2; h = q & 3; }

  float R[64];
  if (is_fwd) {
    const float4* tr = (const float4*)(trans + (size_t)myto * KK + h * 64);
#pragma unroll
    for (int c = 0; c < 16; ++c) {
      float4 v = tr[c];
      R[4*c+0]=expf(v.x); R[4*c+1]=expf(v.y); R[4*c+2]=expf(v.z); R[4*c+3]=expf(v.w);
    }
  } else {
    const float4* tr = (const float4*)(trans + (size_t)myto * KK + h * 32);
#pragma unroll
    for (int c = 0; c < 8; ++c) {
      float4 v = tr[c];
      R[4*c+0]=v.x; R[4*c+1]=v.y; R[4*c+2]=v.z; R[4*c+3]=v.w;
    }
  }

  if (is_fwd) { if (h == 0) P[0][paddr(myto)] = (myto==START_TAG)?1.0f:0.0f; }
  else        { if (h == 0) AV[0][paddr(myto)] = (myto==START_TAG)?0.0f:NEGV; }
  if (tid < 4) redmF[1][tid] = 0.0f;
  __syncthreads();

  const float* fb = feats + (size_t)b * TT * KK + myto;
  uint8_t* bp = bptr + (size_t)b * TT * KK + myto;

  float fcur = fb[0];
  float Mprev = 0.0f;
  float aCarry = 0.0f;
  int cur = 0;

  for (int t = 0; t < TT; ++t) {
    const int tn = (t + 1 < TT) ? t + 1 : t;
    float fnext = fb[(size_t)tn * KK];
    const int rd = (t + 1) & 1, wr = t & 1;

    if (is_fwd) {
      float4 rv = *(const float4*)&redmF[rd][0];
      float M1 = fmaxf(fmaxf(rv.x, rv.y), fmaxf(rv.z, rv.w));
      const float* Pc = &P[cur][0];
      const int base = h * 72;
      float s0=0.f, s1=0.f, s2=0.f, s3=0.f;
#pragma unroll
      for (int c = 0; c < 16; ++c) {
        float4 p = *(const float4*)&Pc[base + (c>>3)*36 + (c&7)*4];
        s0 = fmaf(R[4*c+0], p.x, s0);
        s1 = fmaf(R[4*c+1], p.y, s1);
        s2 = fmaf(R[4*c+2], p.z, s2);
        s3 = fmaf(R[4*c+3], p.w, s3);
      }
      float s = (s0 + s1) + (s2 + s3);
      s = s + dppf<0xB1>(s, s);
      float a = Mprev + logf(s) + fcur;
      float wm = wave_max63(a);
      if (lane == 63) redmF[wr][tid >> 6] = wm;
      float pv = expf(a - M1);
      if (h == 0) P[cur ^ 1][paddr(myto)] = pv;
      Mprev = M1;
      aCarry = a;
    } else {
      const float* Ac = &AV[cur][0];
      const int base = h * 36;
      const int fb0 = h * 32;
      float4 p0 = *(const float4*)&Ac[base];
      float m0 = p0.x + R[0], m1 = p0.y + R[1], m2 = p0.z + R[2], m3 = p0.w + R[3];
      int i0 = fb0, i1 = fb0+1, i2 = fb0+2, i3 = fb0+3;
#pragma unroll
      for (int c = 1; c < 8; ++c) {
        float4 p = *(const float4*)&Ac[base + c*4];
        float v0 = p.x + R[4*c+0]; if (v0 > m0) { m0 = v0; i0 = fb0+4*c+0; }
        float v1 = p.y + R[4*c+1]; if (v1 > m1) { m1 = v1; i1 = fb0+4*c+1; }
        float v2 = p.z + R[4*c+2]; if (v2 > m2) { m2 = v2; i2 = fb0+4*c+2; }
        float v3 = p.w + R[4*c+3]; if (v3 > m3) { m3 = v3; i3 = fb0+4*c+3; }
      }
      float m = m0; int i = i0;
      if (m1 > m || (m1 == m && i1 < i)) { m = m1; i = i1; }
      if (m2 > m || (m2 == m && i2 < i)) { m = m2; i = i2; }
      if (m3 > m || (m3 == m && i3 < i)) { m = m3; i = i3; }
      { float mo = dppf<0xB1>(m, m); int io = dppi<0xB1>(i, i);
        if (mo > m || (mo == m && io < i)) { m = mo; i = io; } }
      { float mo = dppf<0x4E>(m, m); int io = dppi<0x4E>(i, i);
        if (mo > m || (mo == m && io < i)) { m = mo; i = io; } }
      float a = m + fcur;
      if (h == 0) { AV[cur ^ 1][paddr(myto)] = a; bp[(size_t)t * KK] = (uint8_t)i; }
      aCarry = a;
    }
    __syncthreads();
    cur ^= 1;
    fcur = fnext;
  }

  float tstop = trans[(size_t)STOP_TAG * KK + myto];
  float term = aCarry + tstop;
  float M = 0.0f;
  if (is_fwd) {
    float wm = wave_max63(term);
    if (lane == 63) redmF[0][tid >> 6] = wm;
  } else {
    float m = term; int i = myto;
#pragma unroll
    for (int off = 1; off < 64; off <<= 1) {
      float mo = __shfl_xor(m, off, 64);
      int   io = __shfl_xor(i, off, 64);
      if (mo > m || (mo == m && io < i)) { m = mo; i = io; }
    }
    if (lane == 0) { vitm[(tid>>6)-4] = m; viti[(tid>>6)-4] = i; }
  }
  __syncthreads();
  if (is_fwd) {
    float4 rv = *(const float4*)&redmF[0][0];
    M = fmaxf(fmaxf(rv.x, rv.y), fmaxf(rv.z, rv.w));
    float e = (h == 0) ? expf(term - M) : 0.0f;
#pragma unroll
    for (int off = 1; off < 64; off <<= 1) e += __shfl_xor(e, off, 64);
    if (lane == 0) reds[tid >> 6] = e;
  } else if (tid == 256) {
    float m = vitm[0]; int i = viti[0];
#pragma unroll
    for (int w = 1; w < 8; ++w)
      if (vitm[w] > m || (vitm[w] == m && viti[w] < i)) { m = vitm[w]; i = viti[w]; }
    pscore[b] = m; lasttag[b] = i;
  }
  __syncthreads();
  if (tid == 0) logz[b] = M + logf(reds[0] + reds[1] + reds[2] + reds[3]);
}

__global__ __launch_bounds__(256) void backtrace_kernel(
    const uint8_t* __restrict__ bptr, const int* __restrict__ lasttag,
    float* __restrict__ pred)
{
  const int b = blockIdx.x;
  const int tid = threadIdx.x;
  __shared__ __align__(16) uint8_t lb[(TT / 2) * KK];
  __shared__ int tagcarry;
  if (tid == 0) tagcarry = lasttag[b];

  for (int half = 1; half >= 0; --half) {
    __syncthreads();
    const float4* src = reinterpret_cast<const float4*>(
        bptr + ((size_t)b * TT + (size_t)half * (TT / 2)) * KK);
    float4* dst = reinterpret_cast<float4*>(lb);
    for (int i = tid; i < (TT / 2) * KK / 16; i += 256) dst[i] = src[i];
    __syncthreads();
    if (tid == 0) {
      int tag = tagcarry;
      for (int t = TT / 2 - 1; t >= 0; --t) {
        int gt = half * (TT / 2) + t;
        pred[(size_t)b * TT + gt] = (float)tag;
        tag = lb[t * KK + tag];
      }
      tagcarry = tag;
    }
  }
}

__global__ __launch_bounds__(64) void gold_kernel(
    const float* __restrict__ feats, const int* __restrict__ tags,
    const float* __restrict__ trans, const float* __restrict__ logz,
    float* __restrict__ gb)
{
  const int b = blockIdx.x;
  const int lane = threadIdx.x;
  const int* tg = tags + (size_t)b * TT;
  const float* fb = feats + (size_t)b * TT * KK;
  float g = 0.0f;
#pragma unroll
  for (int k = 0; k < TT / 64; ++k) {
    int t = lane * (TT / 64) + k;
    int ct = tg[t];
    int pv = (t == 0) ? START_TAG : tg[t - 1];
    g += trans[ct * KK + pv] + fb[(size_t)t * KK + ct];
  }
  if (lane == 63) g += trans[STOP_TAG * KK + tg[TT - 1]];
#pragma unroll
  for (int off = 1; off <= 32; off <<= 1) g += __shfl_xor(g, off, 64);
  if (lane == 0) gb[b] = logz[b] - g;
}

__global__ __launch_bounds__(256) void loss_reduce(
    const float* __restrict__ gb, float* __restrict__ out)
{
  const int tid = threadIdx.x;
  const int lane = tid & 63, wv = tid >> 6;
  float v = gb[tid];
#pragma unroll
  for (int off = 1; off <= 32; off <<= 1) v += __shfl_xor(v, off, 64);
  __shared__ float red[4];
  if (lane == 0) red[wv] = v;
  __syncthreads();
  if (tid == 0) out[0] = (red[0] + red[1] + red[2] + red[3]) / (float)(BB * TT);
}

// ---------------------------------------------------------------------------
extern "C" void kernel_launch(void* const* d_in, const int* in_sizes, int n_in,
                              void* d_out, int out_size, void* d_ws, size_t ws_size,
                              hipStream_t stream) {
  const float* feats = (const float*)d_in[0];
  const int*   tags  = (const int*)d_in[1];
  const float* trans = (const float*)d_in[2];

  float* out    = (float*)d_out;
  float* loss   = out;
  float* pscore = out + 1;
  float* pred   = out + 1 + BB;
  (void)in_sizes; (void)n_in; (void)out_size;

  const size_t alpha_bytes = (size_t)BB * TT * KK * sizeof(float);   // 64 MB
  const bool cheap = ws_size >= alpha_bytes + 4096;

  if (cheap) {
    float* alphaS  = (float*)d_ws;
    char*  wsend   = (char*)d_ws + alpha_bytes;
    int*   lasttag = (int*)(wsend);
    float* gb      = (float*)(wsend + BB * sizeof(int));
    crf1024<<<BB, 1024, 0, stream>>>(feats, trans, tags, pscore, lasttag,
                                     alphaS, gb);
    backtrace_loss<<<BB + 1, 64, 0, stream>>>(alphaS, trans, lasttag, gb,
                                              pred, loss);
  } else {
    uint8_t* bptr    = (uint8_t*)d_ws;
    char*    wsend   = (char*)d_ws + (size_t)BB * TT * KK;
    float*   logz    = (float*)(wsend);
    int*     lasttag = (int*)(wsend + BB * sizeof(float));
    float*   gb      = (float*)(wsend + BB * sizeof(float) + BB * sizeof(int));
    crf_main_fb<<<BB, 768, 0, stream>>>(feats, trans, logz, pscore, lasttag, bptr);
    backtrace_kernel<<<BB, 256, 0, stream>>>(bptr, lasttag, pred);
    gold_kernel<<<BB, 64, 0, stream>>>(feats, tags, trans, logz, gb);
    loss_reduce<<<1, 256, 0, stream>>>(gb, loss);
  }
}

// Round 10
// 353.629 us; speedup vs baseline: 1.0717x; 1.0717x over previous
//
#include <hip/hip_runtime.h>
#include <cstdint>
#include <cstddef>

#define BB 256
#define TT 512
#define KK 128
#define START_TAG 126
#define STOP_TAG 127
#define NEGV (-10000.0f)
#define NINF (-__builtin_huge_valf())

// ---- DPP helpers -----------------------------------------------------------
template<int CTRL>
__device__ __forceinline__ float dppf(float v, float old) {
  return __int_as_float(__builtin_amdgcn_update_dpp(
      __float_as_int(old), __float_as_int(v), CTRL, 0xf, 0xf, false));
}
template<int CTRL>
__device__ __forceinline__ int dppi(int v, int old) {
  return __builtin_amdgcn_update_dpp(old, v, CTRL, 0xf, 0xf, false);
}
__device__ __forceinline__ float wave_max63(float x) {
  x = fmaxf(x, dppf<0x111>(x, NINF));
  x = fmaxf(x, dppf<0x112>(x, NINF));
  x = fmaxf(x, dppf<0x114>(x, NINF));
  x = fmaxf(x, dppf<0x118>(x, NINF));
  x = fmaxf(x, dppf<0x142>(x, NINF));
  x = fmaxf(x, dppf<0x143>(x, NINF));
  return x;
}
__device__ __forceinline__ float max3f(float a, float b, float c) {
  float d;
  asm("v_max3_f32 %0, %1, %2, %3" : "=v"(d) : "v"(a), "v"(b), "v"(c));
  return d;
}
__device__ __forceinline__ int paddr(int i) { return (i >> 5) * 36 + (i & 31); }

// ---------------------------------------------------------------------------
// crf1024: one block per b, 1024 threads (16 waves).
//   tid [0,512)    : Viterbi values (to=q>>2, h=q&3 -> 32-from slice).
//   tid [512,1024) : forward-alg (same split, exp slice), log-free
//                    multiplicative recurrence, rescale every 4 steps;
//                    fused gold score.
// Transition slice held in 32 NAMED scalar floats (no array -> no scratch,
// no remat). launch_bounds(1024,2): 2 blocks/CU is the thread-count cap
// anyway, so the VGPR budget is 256 - zero pressure.
// LDS reads: 4 distinct float4 addresses per wave (sections h*36 floats =
// h*9 float4s) = R3-proven conflict-free broadcast. One barrier per step.
// ---------------------------------------------------------------------------
__global__ __launch_bounds__(1024, 2) void crf1024(
    const float* __restrict__ feats, const float* __restrict__ trans,
    const int* __restrict__ tags,
    float* __restrict__ pscore, int* __restrict__ lasttag,
    float* __restrict__ alphaS, float* __restrict__ gb)
{
  const int b = blockIdx.x;
  const int tid = threadIdx.x;
  const bool isv = tid < 512;
  const int q = isv ? tid : tid - 512;
  const int to = q >> 2;               // 0..127
  const int h  = q & 3;                // 32-from slice
  const int h9 = h * 9;                // float4 base within padded section
  const int lane = tid & 63;
  const int wv = tid >> 6;             // 0..15

  __shared__ __align__(16) float AV[2][144];   // viterbi alpha (padded)
  __shared__ __align__(16) float P [2][144];   // fwd message (padded)
  __shared__ __align__(16) float pwm[8];       // fwd per-wave P-max
  __shared__ float vitm[2]; __shared__ int viti[2];
  __shared__ float reds[2]; __shared__ float redg[8];

  // 32-from transition slice in NAMED registers: raw (vit) / exp (fwd)
  float R00,R01,R02,R03,R04,R05,R06,R07,R08,R09,R10,R11,R12,R13,R14,R15,
        R16,R17,R18,R19,R20,R21,R22,R23,R24,R25,R26,R27,R28,R29,R30,R31;
  {
    const float4* tr = (const float4*)(trans + (size_t)to * KK + h * 32);
    float4 v;
    v = tr[0]; R00=v.x; R01=v.y; R02=v.z; R03=v.w;
    v = tr[1]; R04=v.x; R05=v.y; R06=v.z; R07=v.w;
    v = tr[2]; R08=v.x; R09=v.y; R10=v.z; R11=v.w;
    v = tr[3]; R12=v.x; R13=v.y; R14=v.z; R15=v.w;
    v = tr[4]; R16=v.x; R17=v.y; R18=v.z; R19=v.w;
    v = tr[5]; R20=v.x; R21=v.y; R22=v.z; R23=v.w;
    v = tr[6]; R24=v.x; R25=v.y; R26=v.z; R27=v.w;
    v = tr[7]; R28=v.x; R29=v.y; R30=v.z; R31=v.w;
    if (!isv) {
      R00=__expf(R00); R01=__expf(R01); R02=__expf(R02); R03=__expf(R03);
      R04=__expf(R04); R05=__expf(R05); R06=__expf(R06); R07=__expf(R07);
      R08=__expf(R08); R09=__expf(R09); R10=__expf(R10); R11=__expf(R11);
      R12=__expf(R12); R13=__expf(R13); R14=__expf(R14); R15=__expf(R15);
      R16=__expf(R16); R17=__expf(R17); R18=__expf(R18); R19=__expf(R19);
      R20=__expf(R20); R21=__expf(R21); R22=__expf(R22); R23=__expf(R23);
      R24=__expf(R24); R25=__expf(R25); R26=__expf(R26); R27=__expf(R27);
      R28=__expf(R28); R29=__expf(R29); R30=__expf(R30); R31=__expf(R31);
    }
  }
  // Belt-and-braces: make values opaque so they cannot be rematerialized.
  asm volatile("" : "+v"(R00),"+v"(R01),"+v"(R02),"+v"(R03),
                    "+v"(R04),"+v"(R05),"+v"(R06),"+v"(R07));
  asm volatile("" : "+v"(R08),"+v"(R09),"+v"(R10),"+v"(R11),
                    "+v"(R12),"+v"(R13),"+v"(R14),"+v"(R15));
  asm volatile("" : "+v"(R16),"+v"(R17),"+v"(R18),"+v"(R19),
                    "+v"(R20),"+v"(R21),"+v"(R22),"+v"(R23));
  asm volatile("" : "+v"(R24),"+v"(R25),"+v"(R26),"+v"(R27),
                    "+v"(R28),"+v"(R29),"+v"(R30),"+v"(R31));

  if (isv) { if (h == 0) AV[0][paddr(to)] = (to==START_TAG)?0.0f:NEGV; }
  else     { if (h == 0) P[0][paddr(to)]  = (to==START_TAG)?1.0f:0.0f; }
  __syncthreads();

  const float* fb = feats + (size_t)b * TT * KK + to;
  float* aSb = alphaS + (size_t)b * TT * KK + to;

  float M = 0.0f;                 // fwd accumulated log-scale
  float fcur = fb[0];
  int cur = 0;

#pragma unroll 4
  for (int t = 0; t < TT; ++t) {
    const int tn = (t + 1 < TT) ? t + 1 : t;
    float fnext = fb[(size_t)tn * KK];

    if (isv) {
      const float4* A4 = (const float4*)&AV[cur][0];
      float4 p = A4[h9];
      float m0 = fmaxf(p.x + R00, p.y + R01);
      float m1 = fmaxf(p.z + R02, p.w + R03);
      p = A4[h9+1]; m0 = max3f(m0, p.x + R04, p.y + R05);
                    m1 = max3f(m1, p.z + R06, p.w + R07);
      p = A4[h9+2]; m0 = max3f(m0, p.x + R08, p.y + R09);
                    m1 = max3f(m1, p.z + R10, p.w + R11);
      p = A4[h9+3]; m0 = max3f(m0, p.x + R12, p.y + R13);
                    m1 = max3f(m1, p.z + R14, p.w + R15);
      p = A4[h9+4]; m0 = max3f(m0, p.x + R16, p.y + R17);
                    m1 = max3f(m1, p.z + R18, p.w + R19);
      p = A4[h9+5]; m0 = max3f(m0, p.x + R20, p.y + R21);
                    m1 = max3f(m1, p.z + R22, p.w + R23);
      p = A4[h9+6]; m0 = max3f(m0, p.x + R24, p.y + R25);
                    m1 = max3f(m1, p.z + R26, p.w + R27);
      p = A4[h9+7]; m0 = max3f(m0, p.x + R28, p.y + R29);
                    m1 = max3f(m1, p.z + R30, p.w + R31);
      float m = fmaxf(m0, m1);
      m = fmaxf(m, dppf<0xB1>(m, m));       // merge h pairs
      m = fmaxf(m, dppf<0x4E>(m, m));       // merge quad
      if (h == 0) {
        float a = m + fcur;
        AV[cur ^ 1][paddr(to)] = a;
        aSb[(size_t)t * KK] = a;            // plain store: keep in L2
      }
    } else {
      float corr = 1.0f;
      if ((t & 3) == 0 && t) {              // consume previous phase-3 maxes
        float4 w0 = *(const float4*)&pwm[0];
        float4 w1 = *(const float4*)&pwm[4];
        float pmax = fmaxf(fmaxf(fmaxf(w0.x, w0.y), fmaxf(w0.z, w0.w)),
                           fmaxf(fmaxf(w1.x, w1.y), fmaxf(w1.z, w1.w)));
        M += __logf(pmax);
        corr = 1.0f / pmax;
      }
      const float4* P4 = (const float4*)&P[cur][0];
      float s0=0.f, s1=0.f, s2=0.f, s3=0.f;
      float4 p = P4[h9];
      s0 = fmaf(R00, p.x, s0); s1 = fmaf(R01, p.y, s1);
      s2 = fmaf(R02, p.z, s2); s3 = fmaf(R03, p.w, s3);
      p = P4[h9+1]; s0 = fmaf(R04, p.x, s0); s1 = fmaf(R05, p.y, s1);
                    s2 = fmaf(R06, p.z, s2); s3 = fmaf(R07, p.w, s3);
      p = P4[h9+2]; s0 = fmaf(R08, p.x, s0); s1 = fmaf(R09, p.y, s1);
                    s2 = fmaf(R10, p.z, s2); s3 = fmaf(R11, p.w, s3);
      p = P4[h9+3]; s0 = fmaf(R12, p.x, s0); s1 = fmaf(R13, p.y, s1);
                    s2 = fmaf(R14, p.z, s2); s3 = fmaf(R15, p.w, s3);
      p = P4[h9+4]; s0 = fmaf(R16, p.x, s0); s1 = fmaf(R17, p.y, s1);
                    s2 = fmaf(R18, p.z, s2); s3 = fmaf(R19, p.w, s3);
      p = P4[h9+5]; s0 = fmaf(R20, p.x, s0); s1 = fmaf(R21, p.y, s1);
                    s2 = fmaf(R22, p.z, s2); s3 = fmaf(R23, p.w, s3);
      p = P4[h9+6]; s0 = fmaf(R24, p.x, s0); s1 = fmaf(R25, p.y, s1);
                    s2 = fmaf(R26, p.z, s2); s3 = fmaf(R27, p.w, s3);
      p = P4[h9+7]; s0 = fmaf(R28, p.x, s0); s1 = fmaf(R29, p.y, s1);
                    s2 = fmaf(R30, p.z, s2); s3 = fmaf(R31, p.w, s3);
      float s = (s0 + s1) + (s2 + s3);
      s = s + dppf<0xB1>(s, s);             // merge h pairs
      s = s + dppf<0x4E>(s, s);             // merge quad
      float ef = __expf(fcur);
      if ((t & 3) == 0 && t) ef *= corr;
      float pv = s * ef;                    // P_new (scaled)
      if (h == 0) P[cur ^ 1][paddr(to)] = pv;
      if ((t & 3) == 3) {                   // publish wave max of P
        float wm = wave_max63(pv);
        if (lane == 63) pwm[wv - 8] = wm;
      }
    }
    __syncthreads();
    cur ^= 1;
    fcur = fnext;
  }

  // ---- terminal ----
  if (tid < KK) {
    // viterbi argmax over final alpha (exact first-index tie rule)
    float term = AV[cur][paddr(tid)] + trans[(size_t)STOP_TAG * KK + tid];
    float m = term; int i = tid;
#pragma unroll
    for (int off = 1; off < 64; off <<= 1) {
      float mo = __shfl_xor(m, off, 64);
      int   io = __shfl_xor(i, off, 64);
      if (mo > m || (mo == m && io < i)) { m = mo; i = io; }
    }
    if (lane == 0) { vitm[tid >> 6] = m; viti[tid >> 6] = i; }
  }
  if (tid >= 512 && tid < 512 + KK) {
    const int to2 = tid - 512;
    float e = P[cur][paddr(to2)] * __expf(trans[(size_t)STOP_TAG * KK + to2]);
#pragma unroll
    for (int off = 1; off < 64; off <<= 1) e += __shfl_xor(e, off, 64);
    if (lane == 0) reds[to2 >> 6] = e;
  }
  if (!isv) {
    // fused gold score: one time-step per fwd thread (q = t)
    const int* tg = tags + (size_t)b * TT;
    const float* fg = feats + (size_t)b * TT * KK;
    int ct = tg[q];
    int pv2 = (q == 0) ? START_TAG : tg[q - 1];
    float g = trans[(size_t)ct * KK + pv2] + fg[(size_t)q * KK + ct];
    if (q == TT - 1) g += trans[(size_t)STOP_TAG * KK + ct];
#pragma unroll
    for (int off = 1; off < 64; off <<= 1) g += __shfl_xor(g, off, 64);
    if (lane == 0) redg[wv - 8] = g;
  }
  __syncthreads();
  if (tid == 0) {
    float m = vitm[0]; int i = viti[0];
    if (vitm[1] > m || (vitm[1] == m && viti[1] < i)) { m = vitm[1]; i = viti[1]; }
    pscore[b] = m; lasttag[b] = i;
  }
  if (tid == 512) {
    float sg = redg[0]+redg[1]+redg[2]+redg[3]+redg[4]+redg[5]+redg[6]+redg[7];
    gb[b] = (M + __logf(reds[0] + reds[1])) - sg;
  }
}

// ---------------------------------------------------------------------------
// backtrace_loss: blocks [0,BB) backtrace per b; block BB reduces loss.
// ---------------------------------------------------------------------------
__global__ __launch_bounds__(64) void backtrace_loss(
    const float* __restrict__ alphaS, const float* __restrict__ trans,
    const int* __restrict__ lasttag, const float* __restrict__ gb,
    float* __restrict__ pred, float* __restrict__ loss_out)
{
  const int lane = threadIdx.x;
  if (blockIdx.x == BB) {
    float v = gb[lane] + gb[lane + 64] + gb[lane + 128] + gb[lane + 192];
#pragma unroll
    for (int off = 1; off < 64; off <<= 1) v += __shfl_xor(v, off, 64);
    if (lane == 0) loss_out[0] = v / (float)(BB * TT);
    return;
  }
  const int b = blockIdx.x;
  __shared__ float tl[KK * KK];                 // 64 KB
  {
    const float4* src = (const float4*)trans;
    float4* dst = (float4*)tl;
#pragma unroll
    for (int i = 0; i < (KK * KK / 4) / 64; ++i) dst[lane + i * 64] = src[lane + i * 64];
  }
  int tag = lasttag[b];
  if (lane == 0) pred[(size_t)b * TT + (TT - 1)] = (float)tag;
  const float* arow = alphaS + (size_t)b * TT * KK;

  float p0[8], p1[8];
#pragma unroll
  for (int j = 0; j < 8; ++j) {
    int r = TT - 2 - j;
    p0[j] = arow[(size_t)r * KK + lane];
    p1[j] = arow[(size_t)r * KK + 64 + lane];
  }
  __syncthreads();

  for (int rb = TT - 2; rb >= 0; rb -= 8) {
#pragma unroll
    for (int j = 0; j < 8; ++j) {
      int r = rb - j;
      if (r >= 0) {
        float x0 = p0[j] + tl[tag * KK + lane];
        float x1 = p1[j] + tl[tag * KK + 64 + lane];
        float m = fmaxf(x0, x1);
        float M = wave_max63(m);
        M = __int_as_float(__builtin_amdgcn_readlane(__float_as_int(M), 63));
        unsigned long long b0 = __ballot(x0 == M);
        unsigned long long b1 = __ballot(x1 == M);
        tag = b0 ? (int)__builtin_ctzll(b0) : 64 + (int)__builtin_ctzll(b1);
        if (lane == 0) pred[(size_t)b * TT + r] = (float)tag;
        int rp = r - 8;
        if (rp >= 0) {
          p0[j] = arow[(size_t)rp * KK + lane];
          p1[j] = arow[(size_t)rp * KK + 64 + lane];
        }
      }
    }
  }
}

// ===========================================================================
// Fallback path (ws too small for 64MB alpha store): R2-proven kernels.
// ===========================================================================
__global__ __launch_bounds__(768) void crf_main_fb(
    const float* __restrict__ feats, const float* __restrict__ trans,
    float* __restrict__ logz, float* __restrict__ pscore,
    int* __restrict__ lasttag, uint8_t* __restrict__ bptr)
{
  const int b = blockIdx.x;
  const int tid = threadIdx.x;
  const bool is_fwd = tid < 256;
  const int lane = tid & 63;

  __shared__ __align__(16) float P[2][144];
  __shared__ __align__(16) float AV[2][144];
  __shared__ __align__(16) float redmF[2][4];
  __shared__ float reds[4];
  __shared__ float vitm[8];
  __shared__ int   viti[8];

  int myto, h;
  if (is_fwd) { myto = tid >> 1; h = tid & 1; }
  else { int q = tid - 256; myto = q >> 2; h = q & 3; }

  float R[64];
  if (is_fwd) {
    const float4* tr = (const float4*)(trans + (size_t)myto * KK + h * 64);
#pragma unroll
    for (int c = 0; c < 16; ++c) {
      float4 v = tr[c];
      R[4*c+0]=expf(v.x); R[4*c+1]=expf(v.y); R[4*c+2]=expf(v.z); R[4*c+3]=expf(v.w);
    }
  } else {
    const float4* tr = (const float4*)(trans + (size_t)myto * KK + h * 32);
#pragma unroll
    for (int c = 0; c < 8; ++c) {
      float4 v = tr[c];
      R[4*c+0]=v.x; R[4*c+1]=v.y; R[4*c+2]=v.z; R[4*c+3]=v.w;
    }
  }

  if (is_fwd) { if (h == 0) P[0][paddr(myto)] = (myto==START_TAG)?1.0f:0.0f; }
  else        { if (h == 0) AV[0][paddr(myto)] = (myto==START_TAG)?0.0f:NEGV; }
  if (tid < 4) redmF[1][tid] = 0.0f;
  __syncthreads();

  const float* fb = feats + (size_t)b * TT * KK + myto;
  uint8_t* bp = bptr + (size_t)b * TT * KK + myto;

  float fcur = fb[0];
  float Mprev = 0.0f;
  float aCarry = 0.0f;
  int cur = 0;

  for (int t = 0; t < TT; ++t) {
    const int tn = (t + 1 < TT) ? t + 1 : t;
    float fnext = fb[(size_t)tn * KK];
    const int rd = (t + 1) & 1, wr = t & 1;

    if (is_fwd) {
      float4 rv = *(const float4*)&redmF[rd][0];
      float M1 = fmaxf(fmaxf(rv.x, rv.y), fmaxf(rv.z, rv.w));
      const float* Pc = &P[cur][0];
      const int base = h * 72;
      float s0=0.f, s1=0.f, s2=0.f, s3=0.f;
#pragma unroll
      for (int c = 0; c < 16; ++c) {
        float4 p = *(const float4*)&Pc[base + (c>>3)*36 + (c&7)*4];
        s0 = fmaf(R[4*c+0], p.x, s0);
        s1 = fmaf(R[4*c+1], p.y, s1);
        s2 = fmaf(R[4*c+2], p.z, s2);
        s3 = fmaf(R[4*c+3], p.w, s3);
      }
      float s = (s0 + s1) + (s2 + s3);
      s = s + dppf<0xB1>(s, s);
      float a = Mprev + logf(s) + fcur;
      float wm = wave_max63(a);
      if (lane == 63) redmF[wr][tid >> 6] = wm;
      float pv = expf(a - M1);
      if (h == 0) P[cur ^ 1][paddr(myto)] = pv;
      Mprev = M1;
      aCarry = a;
    } else {
      const float* Ac = &AV[cur][0];
      const int base = h * 36;
      const int fb0 = h * 32;
      float4 p0 = *(const float4*)&Ac[base];
      float m0 = p0.x + R[0], m1 = p0.y + R[1], m2 = p0.z + R[2], m3 = p0.w + R[3];
      int i0 = fb0, i1 = fb0+1, i2 = fb0+2, i3 = fb0+3;
#pragma unroll
      for (int c = 1; c < 8; ++c) {
        float4 p = *(const float4*)&Ac[base + c*4];
        float v0 = p.x + R[4*c+0]; if (v0 > m0) { m0 = v0; i0 = fb0+4*c+0; }
        float v1 = p.y + R[4*c+1]; if (v1 > m1) { m1 = v1; i1 = fb0+4*c+1; }
        float v2 = p.z + R[4*c+2]; if (v2 > m2) { m2 = v2; i2 = fb0+4*c+2; }
        float v3 = p.w + R[4*c+3]; if (v3 > m3) { m3 = v3; i3 = fb0+4*c+3; }
      }
      float m = m0; int i = i0;
      if (m1 > m || (m1 == m && i1 < i)) { m = m1; i = i1; }
      if (m2 > m || (m2 == m && i2 < i)) { m = m2; i = i2; }
      if (m3 > m || (m3 == m && i3 < i)) { m = m3; i = i3; }
      { float mo = dppf<0xB1>(m, m); int io = dppi<0xB1>(i, i);
        if (mo > m || (mo == m && io < i)) { m = mo; i = io; } }
      { float mo = dppf<0x4E>(m, m); int io = dppi<0x4E>(i, i);
        if (mo > m || (mo == m && io < i)) { m = mo; i = io; } }
      float a = m + fcur;
      if (h == 0) { AV[cur ^ 1][paddr(myto)] = a; bp[(size_t)t * KK] = (uint8_t)i; }
      aCarry = a;
    }
    __syncthreads();
    cur ^= 1;
    fcur = fnext;
  }

  float tstop = trans[(size_t)STOP_TAG * KK + myto];
  float term = aCarry + tstop;
  float M = 0.0f;
  if (is_fwd) {
    float wm = wave_max63(term);
    if (lane == 63) redmF[0][tid >> 6] = wm;
  } else {
    float m = term; int i = myto;
#pragma unroll
    for (int off = 1; off < 64; off <<= 1) {
      float mo = __shfl_xor(m, off, 64);
      int   io = __shfl_xor(i, off, 64);
      if (mo > m || (mo == m && io < i)) { m = mo; i = io; }
    }
    if (lane == 0) { vitm[(tid>>6)-4] = m; viti[(tid>>6)-4] = i; }
  }
  __syncthreads();
  if (is_fwd) {
    float4 rv = *(const float4*)&redmF[0][0];
    M = fmaxf(fmaxf(rv.x, rv.y), fmaxf(rv.z, rv.w));
    float e = (h == 0) ? expf(term - M) : 0.0f;
#pragma unroll
    for (int off = 1; off < 64; off <<= 1) e += __shfl_xor(e, off, 64);
    if (lane == 0) reds[tid >> 6] = e;
  } else if (tid == 256) {
    float m = vitm[0]; int i = viti[0];
#pragma unroll
    for (int w = 1; w < 8; ++w)
      if (vitm[w] > m || (vitm[w] == m && viti[w] < i)) { m = vitm[w]; i = viti[w]; }
    pscore[b] = m; lasttag[b] = i;
  }
  __syncthreads();
  if (tid == 0) logz[b] = M + logf(reds[0] + reds[1] + reds[2] + reds[3]);
}

__global__ __launch_bounds__(256) void backtrace_kernel(
    const uint8_t* __restrict__ bptr, const int* __restrict__ lasttag,
    float* __restrict__ pred)
{
  const int b = blockIdx.x;
  const int tid = threadIdx.x;
  __shared__ __align__(16) uint8_t lb[(TT / 2) * KK];
  __shared__ int tagcarry;
  if (tid == 0) tagcarry = lasttag[b];

  for (int half = 1; half >= 0; --half) {
    __syncthreads();
    const float4* src = reinterpret_cast<const float4*>(
        bptr + ((size_t)b * TT + (size_t)half * (TT / 2)) * KK);
    float4* dst = reinterpret_cast<float4*>(lb);
    for (int i = tid; i < (TT / 2) * KK / 16; i += 256) dst[i] = src[i];
    __syncthreads();
    if (tid == 0) {
      int tag = tagcarry;
      for (int t = TT / 2 - 1; t >= 0; --t) {
        int gt = half * (TT / 2) + t;
        pred[(size_t)b * TT + gt] = (float)tag;
        tag = lb[t * KK + tag];
      }
      tagcarry = tag;
    }
  }
}

__global__ __launch_bounds__(64) void gold_kernel(
    const float* __restrict__ feats, const int* __restrict__ tags,
    const float* __restrict__ trans, const float* __restrict__ logz,
    float* __restrict__ gb)
{
  const int b = blockIdx.x;
  const int lane = threadIdx.x;
  const int* tg = tags + (size_t)b * TT;
  const float* fb = feats + (size_t)b * TT * KK;
  float g = 0.0f;
#pragma unroll
  for (int k = 0; k < TT / 64; ++k) {
    int t = lane * (TT / 64) + k;
    int ct = tg[t];
    int pv = (t == 0) ? START_TAG : tg[t - 1];
    g += trans[ct * KK + pv] + fb[(size_t)t * KK + ct];
  }
  if (lane == 63) g += trans[STOP_TAG * KK + tg[TT - 1]];
#pragma unroll
  for (int off = 1; off <= 32; off <<= 1) g += __shfl_xor(g, off, 64);
  if (lane == 0) gb[b] = logz[b] - g;
}

__global__ __launch_bounds__(256) void loss_reduce(
    const float* __restrict__ gb, float* __restrict__ out)
{
  const int tid = threadIdx.x;
  const int lane = tid & 63, wv = tid >> 6;
  float v = gb[tid];
#pragma unroll
  for (int off = 1; off <= 32; off <<= 1) v += __shfl_xor(v, off, 64);
  __shared__ float red[4];
  if (lane == 0) red[wv] = v;
  __syncthreads();
  if (tid == 0) out[0] = (red[0] + red[1] + red[2] + red[3]) / (float)(BB * TT);
}

// ---------------------------------------------------------------------------
extern "C" void kernel_launch(void* const* d_in, const int* in_sizes, int n_in,
                              void* d_out, int out_size, void* d_ws, size_t ws_size,
                              hipStream_t stream) {
  const float* feats = (const float*)d_in[0];
  const int*   tags  = (const int*)d_in[1];
  const float* trans = (const float*)d_in[2];

  float* out    = (float*)d_out;
  float* loss   = out;
  float* pscore = out + 1;
  float* pred   = out + 1 + BB;
  (void)in_sizes; (void)n_in; (void)out_size;

  const size_t alpha_bytes = (size_t)BB * TT * KK * sizeof(float);   // 64 MB
  const bool cheap = ws_size >= alpha_bytes + 4096;

  if (cheap) {
    float* alphaS  = (float*)d_ws;
    char*  wsend   = (char*)d_ws + alpha_bytes;
    int*   lasttag = (int*)(wsend);
    float* gb      = (float*)(wsend + BB * sizeof(int));
    crf1024<<<BB, 1024, 0, stream>>>(feats, trans, tags, pscore, lasttag,
                                     alphaS, gb);
    backtrace_loss<<<BB + 1, 64, 0, stream>>>(alphaS, trans, lasttag, gb,
                                              pred, loss);
  } else {
    uint8_t* bptr    = (uint8_t*)d_ws;
    char*    wsend   = (char*)d_ws + (size_t)BB * TT * KK;
    float*   logz    = (float*)(wsend);
    int*     lasttag = (int*)(wsend + BB * sizeof(float));
    float*   gb      = (float*)(wsend + BB * sizeof(float) + BB * sizeof(int));
    crf_main_fb<<<BB, 768, 0, stream>>>(feats, trans, logz, pscore, lasttag, bptr);
    backtrace_kernel<<<BB, 256, 0, stream>>>(bptr, lasttag, pred);
    gold_kernel<<<BB, 64, 0, stream>>>(feats, tags, trans, logz, gb);
    loss_reduce<<<1, 256, 0, stream>>>(gb, loss);
  }
}

// Round 11
// 347.923 us; speedup vs baseline: 1.0892x; 1.0164x over previous
//
#include <hip/hip_runtime.h>
#include <cstdint>
#include <cstddef>

#define BB 256
#define TT 512
#define KK 128
#define START_TAG 126
#define STOP_TAG 127
#define NEGV (-10000.0f)
#define NINF (-__builtin_huge_valf())

// ---- DPP helpers -----------------------------------------------------------
template<int CTRL>
__device__ __forceinline__ float dppf(float v, float old) {
  return __int_as_float(__builtin_amdgcn_update_dpp(
      __float_as_int(old), __float_as_int(v), CTRL, 0xf, 0xf, false));
}
template<int CTRL>
__device__ __forceinline__ int dppi(int v, int old) {
  return __builtin_amdgcn_update_dpp(old, v, CTRL, 0xf, 0xf, false);
}
__device__ __forceinline__ float wave_max63(float x) {
  x = fmaxf(x, dppf<0x111>(x, NINF));
  x = fmaxf(x, dppf<0x112>(x, NINF));
  x = fmaxf(x, dppf<0x114>(x, NINF));
  x = fmaxf(x, dppf<0x118>(x, NINF));
  x = fmaxf(x, dppf<0x142>(x, NINF));
  x = fmaxf(x, dppf<0x143>(x, NINF));
  return x;
}
__device__ __forceinline__ float max3f(float a, float b, float c) {
  float d;
  asm("v_max3_f32 %0, %1, %2, %3" : "=v"(d) : "v"(a), "v"(b), "v"(c));
  return d;
}
__device__ __forceinline__ int paddr(int i) { return (i >> 5) * 36 + (i & 31); }

// ---------------------------------------------------------------------------
// crf256: grid 2*BB blocks x 256 threads (4 waves) - the ONLY block size at
// which the allocator demonstrably grants ~170 VGPRs (R1: 168, R6: 172).
//   block [0,BB)    : Viterbi values for b (2 thr/to, R[64] raw slice),
//                     exact alpha rows -> ws.
//   block [BB,2*BB) : forward-alg (R[64] exp slice), log-free recurrence,
//                     rescale every 4 steps; fused gold score -> gb.
// Padded LDS sections (h*72 base, 36-float sections) = R3-proven 0-conflict
// 2-address broadcast. One barrier per step.
// ---------------------------------------------------------------------------
__global__ __launch_bounds__(256, 1) void crf256(
    const float* __restrict__ feats, const float* __restrict__ trans,
    const int* __restrict__ tags,
    float* __restrict__ pscore, int* __restrict__ lasttag,
    float* __restrict__ alphaS, float* __restrict__ gb)
{
  const int bid = blockIdx.x;
  const bool isv = bid < BB;
  const int b = isv ? bid : bid - BB;
  const int tid = threadIdx.x;
  const int to = tid >> 1;             // 0..127
  const int h  = tid & 1;              // 64-from slice
  const int lane = tid & 63;
  const int wv = tid >> 6;             // 0..3

  __shared__ __align__(16) float BUF[2][144];  // AV (vit) / P (fwd), padded
  __shared__ __align__(16) float pwm[4];       // fwd per-wave P-max
  __shared__ float vitm[2]; __shared__ int viti[2];
  __shared__ float reds[2]; __shared__ float redg[4];

  // 64-from transition slice in registers: raw (vit) / exp (fwd)
  float R[64];
  {
    const float4* tr = (const float4*)(trans + (size_t)to * KK + h * 64);
#pragma unroll
    for (int c = 0; c < 16; ++c) {
      float4 v = tr[c];
      if (isv) { R[4*c+0]=v.x; R[4*c+1]=v.y; R[4*c+2]=v.z; R[4*c+3]=v.w; }
      else     { R[4*c+0]=__expf(v.x); R[4*c+1]=__expf(v.y);
                 R[4*c+2]=__expf(v.z); R[4*c+3]=__expf(v.w); }
    }
  }

  if (h == 0) BUF[0][paddr(to)] = isv ? ((to==START_TAG)?0.0f:NEGV)
                                      : ((to==START_TAG)?1.0f:0.0f);
  __syncthreads();

  const float* fb = feats + (size_t)b * TT * KK + to;
  float* aSb = alphaS + (size_t)b * TT * KK + to;

  float M = 0.0f;                 // fwd accumulated log-scale
  float fcur = fb[0];
  int cur = 0;

#pragma unroll 4
  for (int t = 0; t < TT; ++t) {
    const int tn = (t + 1 < TT) ? t + 1 : t;
    float fnext = fb[(size_t)tn * KK];
    const float* Bc = &BUF[cur][0];
    const int base = h * 72;

    if (isv) {
      float4 p = *(const float4*)&Bc[base];
      float m0 = fmaxf(p.x + R[0], p.y + R[1]);
      float m1 = fmaxf(p.z + R[2], p.w + R[3]);
#pragma unroll
      for (int c = 1; c < 16; ++c) {
        p = *(const float4*)&Bc[base + (c>>3)*36 + (c&7)*4];
        m0 = max3f(m0, p.x + R[4*c+0], p.y + R[4*c+1]);
        m1 = max3f(m1, p.z + R[4*c+2], p.w + R[4*c+3]);
      }
      float m = fmaxf(m0, m1);
      m = fmaxf(m, dppf<0xB1>(m, m));       // merge h pair
      if (h == 0) {
        float a = m + fcur;
        BUF[cur ^ 1][paddr(to)] = a;
        aSb[(size_t)t * KK] = a;
      }
    } else {
      float corr = 1.0f;
      if ((t & 3) == 0 && t) {              // consume previous phase-3 maxes
        float4 w = *(const float4*)&pwm[0];
        float pmax = fmaxf(fmaxf(w.x, w.y), fmaxf(w.z, w.w));
        M += __logf(pmax);
        corr = 1.0f / pmax;
      }
      float s0=0.f, s1=0.f, s2=0.f, s3=0.f;
#pragma unroll
      for (int c = 0; c < 16; ++c) {
        float4 p = *(const float4*)&Bc[base + (c>>3)*36 + (c&7)*4];
        s0 = fmaf(R[4*c+0], p.x, s0);
        s1 = fmaf(R[4*c+1], p.y, s1);
        s2 = fmaf(R[4*c+2], p.z, s2);
        s3 = fmaf(R[4*c+3], p.w, s3);
      }
      float s = (s0 + s1) + (s2 + s3);
      s = s + dppf<0xB1>(s, s);             // merge h pair -> full row sum
      float ef = __expf(fcur);
      if ((t & 3) == 0 && t) ef *= corr;
      float pv = s * ef;                    // P_new (scaled)
      if (h == 0) BUF[cur ^ 1][paddr(to)] = pv;
      if ((t & 3) == 3) {                   // publish wave max of P
        float wm = wave_max63(pv);
        if (lane == 63) pwm[wv] = wm;
      }
    }
    __syncthreads();
    cur ^= 1;
    fcur = fnext;
  }

  // ---- terminal ----
  if (isv) {
    if (tid < KK) {
      float term = BUF[cur][paddr(tid)] + trans[(size_t)STOP_TAG * KK + tid];
      float m = term; int i = tid;
#pragma unroll
      for (int off = 1; off < 64; off <<= 1) {
        float mo = __shfl_xor(m, off, 64);
        int   io = __shfl_xor(i, off, 64);
        if (mo > m || (mo == m && io < i)) { m = mo; i = io; }
      }
      if (lane == 0) { vitm[tid >> 6] = m; viti[tid >> 6] = i; }
    }
    __syncthreads();
    if (tid == 0) {
      float m = vitm[0]; int i = viti[0];
      if (vitm[1] > m || (vitm[1] == m && viti[1] < i)) { m = vitm[1]; i = viti[1]; }
      pscore[b] = m; lasttag[b] = i;
    }
  } else {
    if (tid < KK) {
      float e = BUF[cur][paddr(tid)] * __expf(trans[(size_t)STOP_TAG * KK + tid]);
#pragma unroll
      for (int off = 1; off < 64; off <<= 1) e += __shfl_xor(e, off, 64);
      if (lane == 0) reds[tid >> 6] = e;
    }
    // fused gold score: 2 time-steps per thread
    const int* tg = tags + (size_t)b * TT;
    const float* fg = feats + (size_t)b * TT * KK;
    float g = 0.0f;
#pragma unroll
    for (int k2 = 0; k2 < 2; ++k2) {
      int t = tid + k2 * 256;
      int ct = tg[t];
      int pv2 = (t == 0) ? START_TAG : tg[t - 1];
      g += trans[(size_t)ct * KK + pv2] + fg[(size_t)t * KK + ct];
      if (t == TT - 1) g += trans[(size_t)STOP_TAG * KK + ct];
    }
#pragma unroll
    for (int off = 1; off < 64; off <<= 1) g += __shfl_xor(g, off, 64);
    if (lane == 0) redg[wv] = g;
    __syncthreads();
    if (tid == 0) {
      float sg = redg[0] + redg[1] + redg[2] + redg[3];
      gb[b] = (M + __logf(reds[0] + reds[1])) - sg;
    }
  }
}

// ---------------------------------------------------------------------------
// backtrace_loss: blocks [0,BB) backtrace per b; block BB reduces loss.
// ---------------------------------------------------------------------------
__global__ __launch_bounds__(64) void backtrace_loss(
    const float* __restrict__ alphaS, const float* __restrict__ trans,
    const int* __restrict__ lasttag, const float* __restrict__ gb,
    float* __restrict__ pred, float* __restrict__ loss_out)
{
  const int lane = threadIdx.x;
  if (blockIdx.x == BB) {
    float v = gb[lane] + gb[lane + 64] + gb[lane + 128] + gb[lane + 192];
#pragma unroll
    for (int off = 1; off < 64; off <<= 1) v += __shfl_xor(v, off, 64);
    if (lane == 0) loss_out[0] = v / (float)(BB * TT);
    return;
  }
  const int b = blockIdx.x;
  __shared__ float tl[KK * KK];                 // 64 KB
  {
    const float4* src = (const float4*)trans;
    float4* dst = (float4*)tl;
#pragma unroll
    for (int i = 0; i < (KK * KK / 4) / 64; ++i) dst[lane + i * 64] = src[lane + i * 64];
  }
  int tag = lasttag[b];
  if (lane == 0) pred[(size_t)b * TT + (TT - 1)] = (float)tag;
  const float* arow = alphaS + (size_t)b * TT * KK;

  float p0[8], p1[8];
#pragma unroll
  for (int j = 0; j < 8; ++j) {
    int r = TT - 2 - j;
    p0[j] = arow[(size_t)r * KK + lane];
    p1[j] = arow[(size_t)r * KK + 64 + lane];
  }
  __syncthreads();

  for (int rb = TT - 2; rb >= 0; rb -= 8) {
#pragma unroll
    for (int j = 0; j < 8; ++j) {
      int r = rb - j;
      if (r >= 0) {
        float x0 = p0[j] + tl[tag * KK + lane];
        float x1 = p1[j] + tl[tag * KK + 64 + lane];
        float m = fmaxf(x0, x1);
        float M = wave_max63(m);
        M = __int_as_float(__builtin_amdgcn_readlane(__float_as_int(M), 63));
        unsigned long long b0 = __ballot(x0 == M);
        unsigned long long b1 = __ballot(x1 == M);
        tag = b0 ? (int)__builtin_ctzll(b0) : 64 + (int)__builtin_ctzll(b1);
        if (lane == 0) pred[(size_t)b * TT + r] = (float)tag;
        int rp = r - 8;
        if (rp >= 0) {
          p0[j] = arow[(size_t)rp * KK + lane];
          p1[j] = arow[(size_t)rp * KK + 64 + lane];
        }
      }
    }
  }
}

// ===========================================================================
// Fallback path (ws too small for 64MB alpha store): R2-proven kernels.
// ===========================================================================
__global__ __launch_bounds__(768) void crf_main_fb(
    const float* __restrict__ feats, const float* __restrict__ trans,
    float* __restrict__ logz, float* __restrict__ pscore,
    int* __restrict__ lasttag, uint8_t* __restrict__ bptr)
{
  const int b = blockIdx.x;
  const int tid = threadIdx.x;
  const bool is_fwd = tid < 256;
  const int lane = tid & 63;

  __shared__ __align__(16) float P[2][144];
  __shared__ __align__(16) float AV[2][144];
  __shared__ __align__(16) float redmF[2][4];
  __shared__ float reds[4];
  __shared__ float vitm[8];
  __shared__ int   viti[8];

  int myto, h;
  if (is_fwd) { myto = tid >> 1; h = tid & 1; }
  else { int q = tid - 256; myto = q >> 2; h = q & 3; }

  float R[64];
  if (is_fwd) {
    const float4* tr = (const float4*)(trans + (size_t)myto * KK + h * 64);
#pragma unroll
    for (int c = 0; c < 16; ++c) {
      float4 v = tr[c];
      R[4*c+0]=expf(v.x); R[4*c+1]=expf(v.y); R[4*c+2]=expf(v.z); R[4*c+3]=expf(v.w);
    }
  } else {
    const float4* tr = (const float4*)(trans + (size_t)myto * KK + h * 32);
#pragma unroll
    for (int c = 0; c < 8; ++c) {
      float4 v = tr[c];
      R[4*c+0]=v.x; R[4*c+1]=v.y; R[4*c+2]=v.z; R[4*c+3]=v.w;
    }
  }

  if (is_fwd) { if (h == 0) P[0][paddr(myto)] = (myto==START_TAG)?1.0f:0.0f; }
  else        { if (h == 0) AV[0][paddr(myto)] = (myto==START_TAG)?0.0f:NEGV; }
  if (tid < 4) redmF[1][tid] = 0.0f;
  __syncthreads();

  const float* fb = feats + (size_t)b * TT * KK + myto;
  uint8_t* bp = bptr + (size_t)b * TT * KK + myto;

  float fcur = fb[0];
  float Mprev = 0.0f;
  float aCarry = 0.0f;
  int cur = 0;

  for (int t = 0; t < TT; ++t) {
    const int tn = (t + 1 < TT) ? t + 1 : t;
    float fnext = fb[(size_t)tn * KK];
    const int rd = (t + 1) & 1, wr = t & 1;

    if (is_fwd) {
      float4 rv = *(const float4*)&redmF[rd][0];
      float M1 = fmaxf(fmaxf(rv.x, rv.y), fmaxf(rv.z, rv.w));
      const float* Pc = &P[cur][0];
      const int base = h * 72;
      float s0=0.f, s1=0.f, s2=0.f, s3=0.f;
#pragma unroll
      for (int c = 0; c < 16; ++c) {
        float4 p = *(const float4*)&Pc[base + (c>>3)*36 + (c&7)*4];
        s0 = fmaf(R[4*c+0], p.x, s0);
        s1 = fmaf(R[4*c+1], p.y, s1);
        s2 = fmaf(R[4*c+2], p.z, s2);
        s3 = fmaf(R[4*c+3], p.w, s3);
      }
      float s = (s0 + s1) + (s2 + s3);
      s = s + dppf<0xB1>(s, s);
      float a = Mprev + logf(s) + fcur;
      float wm = wave_max63(a);
      if (lane == 63) redmF[wr][tid >> 6] = wm;
      float pv = expf(a - M1);
      if (h == 0) P[cur ^ 1][paddr(myto)] = pv;
      Mprev = M1;
      aCarry = a;
    } else {
      const float* Ac = &AV[cur][0];
      const int base = h * 36;
      const int fb0 = h * 32;
      float4 p0 = *(const float4*)&Ac[base];
      float m0 = p0.x + R[0], m1 = p0.y + R[1], m2 = p0.z + R[2], m3 = p0.w + R[3];
      int i0 = fb0, i1 = fb0+1, i2 = fb0+2, i3 = fb0+3;
#pragma unroll
      for (int c = 1; c < 8; ++c) {
        float4 p = *(const float4*)&Ac[base + c*4];
        float v0 = p.x + R[4*c+0]; if (v0 > m0) { m0 = v0; i0 = fb0+4*c+0; }
        float v1 = p.y + R[4*c+1]; if (v1 > m1) { m1 = v1; i1 = fb0+4*c+1; }
        float v2 = p.z + R[4*c+2]; if (v2 > m2) { m2 = v2; i2 = fb0+4*c+2; }
        float v3 = p.w + R[4*c+3]; if (v3 > m3) { m3 = v3; i3 = fb0+4*c+3; }
      }
      float m = m0; int i = i0;
      if (m1 > m || (m1 == m && i1 < i)) { m = m1; i = i1; }
      if (m2 > m || (m2 == m && i2 < i)) { m = m2; i = i2; }
      if (m3 > m || (m3 == m && i3 < i)) { m = m3; i = i3; }
      { float mo = dppf<0xB1>(m, m); int io = dppi<0xB1>(i, i);
        if (mo > m || (mo == m && io < i)) { m = mo; i = io; } }
      { float mo = dppf<0x4E>(m, m); int io = dppi<0x4E>(i, i);
        if (mo > m || (mo == m && io < i)) { m = mo; i = io; } }
      float a = m + fcur;
      if (h == 0) { AV[cur ^ 1][paddr(myto)] = a; bp[(size_t)t * KK] = (uint8_t)i; }
      aCarry = a;
    }
    __syncthreads();
    cur ^= 1;
    fcur = fnext;
  }

  float tstop = trans[(size_t)STOP_TAG * KK + myto];
  float term = aCarry + tstop;
  float M = 0.0f;
  if (is_fwd) {
    float wm = wave_max63(term);
    if (lane == 63) redmF[0][tid >> 6] = wm;
  } else {
    float m = term; int i = myto;
#pragma unroll
    for (int off = 1; off < 64; off <<= 1) {
      float mo = __shfl_xor(m, off, 64);
      int   io = __shfl_xor(i, off, 64);
      if (mo > m || (mo == m && io < i)) { m = mo; i = io; }
    }
    if (lane == 0) { vitm[(tid>>6)-4] = m; viti[(tid>>6)-4] = i; }
  }
  __syncthreads();
  if (is_fwd) {
    float4 rv = *(const float4*)&redmF[0][0];
    M = fmaxf(fmaxf(rv.x, rv.y), fmaxf(rv.z, rv.w));
    float e = (h == 0) ? expf(term - M) : 0.0f;
#pragma unroll
    for (int off = 1; off < 64; off <<= 1) e += __shfl_xor(e, off, 64);
    if (lane == 0) reds[tid >> 6] = e;
  } else if (tid == 256) {
    float m = vitm[0]; int i = viti[0];
#pragma unroll
    for (int w = 1; w < 8; ++w)
      if (vitm[w] > m || (vitm[w] == m && viti[w] < i)) { m = vitm[w]; i = viti[w]; }
    pscore[b] = m; lasttag[b] = i;
  }
  __syncthreads();
  if (tid == 0) logz[b] = M + logf(reds[0] + reds[1] + reds[2] + reds[3]);
}

__global__ __launch_bounds__(256) void backtrace_kernel(
    const uint8_t* __restrict__ bptr, const int* __restrict__ lasttag,
    float* __restrict__ pred)
{
  const int b = blockIdx.x;
  const int tid = threadIdx.x;
  __shared__ __align__(16) uint8_t lb[(TT / 2) * KK];
  __shared__ int tagcarry;
  if (tid == 0) tagcarry = lasttag[b];

  for (int half = 1; half >= 0; --half) {
    __syncthreads();
    const float4* src = reinterpret_cast<const float4*>(
        bptr + ((size_t)b * TT + (size_t)half * (TT / 2)) * KK);
    float4* dst = reinterpret_cast<float4*>(lb);
    for (int i = tid; i < (TT / 2) * KK / 16; i += 256) dst[i] = src[i];
    __syncthreads();
    if (tid == 0) {
      int tag = tagcarry;
      for (int t = TT / 2 - 1; t >= 0; --t) {
        int gt = half * (TT / 2) + t;
        pred[(size_t)b * TT + gt] = (float)tag;
        tag = lb[t * KK + tag];
      }
      tagcarry = tag;
    }
  }
}

__global__ __launch_bounds__(64) void gold_kernel(
    const float* __restrict__ feats, const int* __restrict__ tags,
    const float* __restrict__ trans, const float* __restrict__ logz,
    float* __restrict__ gb)
{
  const int b = blockIdx.x;
  const int lane = threadIdx.x;
  const int* tg = tags + (size_t)b * TT;
  const float* fb = feats + (size_t)b * TT * KK;
  float g = 0.0f;
#pragma unroll
  for (int k = 0; k < TT / 64; ++k) {
    int t = lane * (TT / 64) + k;
    int ct = tg[t];
    int pv = (t == 0) ? START_TAG : tg[t - 1];
    g += trans[ct * KK + pv] + fb[(size_t)t * KK + ct];
  }
  if (lane == 63) g += trans[STOP_TAG * KK + tg[TT - 1]];
#pragma unroll
  for (int off = 1; off <= 32; off <<= 1) g += __shfl_xor(g, off, 64);
  if (lane == 0) gb[b] = logz[b] - g;
}

__global__ __launch_bounds__(256) void loss_reduce(
    const float* __restrict__ gb, float* __restrict__ out)
{
  const int tid = threadIdx.x;
  const int lane = tid & 63, wv = tid >> 6;
  float v = gb[tid];
#pragma unroll
  for (int off = 1; off <= 32; off <<= 1) v += __shfl_xor(v, off, 64);
  __shared__ float red[4];
  if (lane == 0) red[wv] = v;
  __syncthreads();
  if (tid == 0) out[0] = (red[0] + red[1] + red[2] + red[3]) / (float)(BB * TT);
}

// ---------------------------------------------------------------------------
extern "C" void kernel_launch(void* const* d_in, const int* in_sizes, int n_in,
                              void* d_out, int out_size, void* d_ws, size_t ws_size,
                              hipStream_t stream) {
  const float* feats = (const float*)d_in[0];
  const int*   tags  = (const int*)d_in[1];
  const float* trans = (const float*)d_in[2];

  float* out    = (float*)d_out;
  float* loss   = out;
  float* pscore = out + 1;
  float* pred   = out + 1 + BB;
  (void)in_sizes; (void)n_in; (void)out_size;

  const size_t alpha_bytes = (size_t)BB * TT * KK * sizeof(float);   // 64 MB
  const bool cheap = ws_size >= alpha_bytes + 4096;

  if (cheap) {
    float* alphaS  = (float*)d_ws;
    char*  wsend   = (char*)d_ws + alpha_bytes;
    int*   lasttag = (int*)(wsend);
    float* gb      = (float*)(wsend + BB * sizeof(int));
    crf256<<<2 * BB, 256, 0, stream>>>(feats, trans, tags, pscore, lasttag,
                                       alphaS, gb);
    backtrace_loss<<<BB + 1, 64, 0, stream>>>(alphaS, trans, lasttag, gb,
                                              pred, loss);
  } else {
    uint8_t* bptr    = (uint8_t*)d_ws;
    char*    wsend   = (char*)d_ws + (size_t)BB * TT * KK;
    float*   logz    = (float*)(wsend);
    int*     lasttag = (int*)(wsend + BB * sizeof(float));
    float*   gb      = (float*)(wsend + BB * sizeof(float) + BB * sizeof(int));
    crf_main_fb<<<BB, 768, 0, stream>>>(feats, trans, logz, pscore, lasttag, bptr);
    backtrace_kernel<<<BB, 256, 0, stream>>>(bptr, lasttag, pred);
    gold_kernel<<<BB, 64, 0, stream>>>(feats, tags, trans, logz, gb);
    loss_reduce<<<1, 256, 0, stream>>>(gb, loss);
  }
}